// Round 6
// baseline (384.877 us; speedup 1.0000x reference)
//
#include <hip/hip_runtime.h>

typedef unsigned short ushort;
typedef __attribute__((ext_vector_type(8))) __bf16 bf16x8;
typedef __attribute__((ext_vector_type(8))) ushort ushort8;
typedef __attribute__((ext_vector_type(4))) float f32x4;
typedef __attribute__((ext_vector_type(16))) float f32x16;
typedef __attribute__((ext_vector_type(4))) unsigned u32x4;

#define DM 2048
#define NH 16
#define DK 128
#define BATCH 2
#define SEQ 2048
#define MROWS (BATCH*SEQ)   // 4096

#define GLDS16(g, l) __builtin_amdgcn_global_load_lds(                         \
    (const __attribute__((address_space(1))) void*)(g),                        \
    (__attribute__((address_space(3))) void*)(l), 16, 0, 0)

__device__ __forceinline__ ushort f2bf(float f) {
  unsigned u = __builtin_bit_cast(unsigned, f);
  u += 0x7fffu + ((u >> 16) & 1u);
  return (ushort)(u >> 16);
}

__device__ __forceinline__ unsigned cvtpk(float lo, float hi) {
  unsigned r;
  asm("v_cvt_pk_bf16_f32 %0, %1, %2" : "=v"(r) : "v"(lo), "v"(hi));
  return r;
}

// ---------------- f32 -> bf16 convert (x + 4 weights, one launch) ----------------
__global__ __launch_bounds__(256) void cvt_all(const float* __restrict__ x,
                                               const float* __restrict__ w0,
                                               const float* __restrict__ w1,
                                               const float* __restrict__ w2,
                                               const float* __restrict__ w3,
                                               ushort* __restrict__ xb,
                                               ushort* __restrict__ o0,
                                               ushort* __restrict__ o1,
                                               ushort* __restrict__ o2,
                                               ushort* __restrict__ o3) {
  int b = blockIdx.x;
  const float* src;
  ushort* dst;
  int lb;
  if (b < 4096) { src = x; dst = xb; lb = b; }
  else {
    int wsel = (b - 4096) >> 11;
    lb = (b - 4096) & 2047;
    src = (wsel == 0) ? w0 : (wsel == 1) ? w1 : (wsel == 2) ? w2 : w3;
    dst = (wsel == 0) ? o0 : (wsel == 1) ? o1 : (wsel == 2) ? o2 : o3;
  }
  int i = lb * 256 + threadIdx.x;
  const float4* p = (const float4*)src;
  float4 a = p[2 * i], bq = p[2 * i + 1];
  ushort8 o;
  o[0] = f2bf(a.x); o[1] = f2bf(a.y); o[2] = f2bf(a.z); o[3] = f2bf(a.w);
  o[4] = f2bf(bq.x); o[5] = f2bf(bq.y); o[6] = f2bf(bq.z); o[7] = f2bf(bq.w);
  *(ushort8*)(dst + (size_t)8 * i) = o;
}

// ---- fused multi-weight GEMM, BM=128 BN=128 BK=32, 8 waves (2M x 4N), 2 blocks/CU ----
// C_w = A(MxK) * B_w^T for NW weights sharing A. Wave-tile 64x32 per weight.
// Double-buffered 2x(1+NW)*8KB LDS; counted vmcnt(LPT=1+NW): wait tile-t loads
// BEFORE compute while tile-t+1 stays in flight; stage(t+2) after the read-barrier.
// BK=32 row stride (64B) gives the uniform 8-lane/bank-start b128 floor -> no swizzle.
// MODE 0: write bf16 scattered to (B,H,S,DK) per weight. MODE 1: write f32 MxN.
template <int NW, int MODE>
__device__ __forceinline__ void gemmF_body(const ushort* __restrict__ A,
                                           const ushort* __restrict__ B0,
                                           const ushort* __restrict__ B1,
                                           const ushort* __restrict__ B2,
                                           ushort* __restrict__ O0,
                                           ushort* __restrict__ O1,
                                           ushort* __restrict__ O2,
                                           float* __restrict__ ofp,
                                           int row0, int col0) {
  extern __shared__ ushort lds[];
  constexpr int NT = DM / 32;                 // 64 K-tiles
  constexpr int BUFSZ = 4096 * (1 + NW);      // ushorts per buffer
  const ushort* Bw[3] = {B0, B1, B2};
  ushort* Ow[3] = {O0, O1, O2};
  const int tid = threadIdx.x;
  const int wid = tid >> 6, lane = tid & 63;
  const int l15 = lane & 15, lhi = lane >> 4;
  const int wm = wid >> 2, wn = wid & 3;

  f32x4 acc[4][NW * 2];
  const f32x4 z4 = {0.f, 0.f, 0.f, 0.f};
#pragma unroll
  for (int mq = 0; mq < 4; ++mq)
#pragma unroll
    for (int i = 0; i < NW * 2; ++i) acc[mq][i] = z4;

  const int sr = tid >> 2, sc = tid & 3;  // staging granule: row, col16B
  auto stage = [&](int kt, int buf) {
    ushort* base = &lds[buf * BUFSZ];
    const ushort* srcA = A + (size_t)row0 * DM + kt * 32;
    GLDS16(srcA + (size_t)sr * DM + sc * 8, base + wid * 512);
#pragma unroll
    for (int w3 = 0; w3 < NW; ++w3) {
      const ushort* srcB = Bw[w3] + (size_t)col0 * DM + kt * 32;
      GLDS16(srcB + (size_t)sr * DM + sc * 8, base + 4096 + w3 * 4096 + wid * 512);
    }
  };

  stage(0, 0);
  stage(1, 1);

  for (int t = 0; t < NT; ++t) {
    if (t + 1 < NT) {
      if constexpr (NW == 3)
        asm volatile("s_waitcnt vmcnt(4)" ::: "memory");
      else
        asm volatile("s_waitcnt vmcnt(2)" ::: "memory");
    } else {
      asm volatile("s_waitcnt vmcnt(0)" ::: "memory");
    }
    __builtin_amdgcn_s_barrier();  // all waves' tile-t loads landed

    const ushort* Ab = &lds[(t & 1) * BUFSZ];
    bf16x8 af[4];
#pragma unroll
    for (int mq = 0; mq < 4; ++mq)
      af[mq] = *(const bf16x8*)&Ab[(wm * 64 + mq * 16 + l15) * 32 + lhi * 8];
#pragma unroll
    for (int w3 = 0; w3 < NW; ++w3) {
      const ushort* Bb = Ab + 4096 + w3 * 4096;
      bf16x8 bfr[2];
#pragma unroll
      for (int n = 0; n < 2; ++n)
        bfr[n] = *(const bf16x8*)&Bb[(wn * 32 + n * 16 + l15) * 32 + lhi * 8];
      __builtin_amdgcn_s_setprio(1);
#pragma unroll
      for (int mq = 0; mq < 4; ++mq)
#pragma unroll
        for (int n = 0; n < 2; ++n)
          acc[mq][w3 * 2 + n] = __builtin_amdgcn_mfma_f32_16x16x32_bf16(
              af[mq], bfr[n], acc[mq][w3 * 2 + n], 0, 0, 0);
      __builtin_amdgcn_s_setprio(0);
    }

    __builtin_amdgcn_s_barrier();  // all waves done reading buf[t&1]
    if (t + 2 < NT) stage(t + 2, t & 1);
  }

  // epilogue
#pragma unroll
  for (int mq = 0; mq < 4; ++mq) {
    int grow = row0 + wm * 64 + mq * 16 + lhi * 4;
#pragma unroll
    for (int w3 = 0; w3 < NW; ++w3)
#pragma unroll
      for (int n = 0; n < 2; ++n) {
        int gcol = col0 + wn * 32 + n * 16 + l15;
#pragma unroll
        for (int j = 0; j < 4; ++j) {
          float v = acc[mq][w3 * 2 + n][j];
          int r = grow + j;
          if (MODE == 0) {
            int b = r >> 11, s = r & (SEQ - 1);
            int h = gcol >> 7, d = gcol & (DK - 1);
            Ow[w3][((size_t)(b * NH + h) * SEQ + s) * DK + d] = f2bf(v);
          } else {
            ofp[(size_t)r * DM + gcol] = v;
          }
        }
      }
  }
}

__global__ __launch_bounds__(512, 4) void gemmF_qkv(const ushort* __restrict__ A,
                                                    const ushort* __restrict__ W0,
                                                    const ushort* __restrict__ W1,
                                                    const ushort* __restrict__ W2,
                                                    ushort* __restrict__ O0,
                                                    ushort* __restrict__ O1,
                                                    ushort* __restrict__ O2) {
  // 512 blocks, grid 32r x 16c; XCD (bid&7) owns 16 rows x 4 cols (fill-min chunk)
  int xcd = (int)blockIdx.x & 7, i = (int)blockIdx.x >> 3;
  int row0 = (((xcd >> 2) << 4) + (i >> 2)) * 128;
  int col0 = (((xcd & 3) << 2) + (i & 3)) * 128;
  gemmF_body<3, 0>(A, W0, W1, W2, O0, O1, O2, nullptr, row0, col0);
}

__global__ __launch_bounds__(512, 4) void gemmF_out(const ushort* __restrict__ A,
                                                    const ushort* __restrict__ Bm,
                                                    float* __restrict__ ofp) {
  // 512 blocks, grid 32r x 16c; XCD owns 8 rows x 8 cols (A and W same weight here)
  int xcd = (int)blockIdx.x & 7, i = (int)blockIdx.x >> 3;
  int row0 = (((xcd >> 1) << 3) + (i >> 3)) * 128;
  int col0 = (((xcd & 1) << 3) + (i & 7)) * 128;
  gemmF_body<1, 1>(A, Bm, nullptr, nullptr, nullptr, nullptr, nullptr, ofp, row0, col0);
}

// ---------------- RoPE in-place on Q and K, (B,H,S,DK) bf16, one launch ----------------
__global__ __launch_bounds__(256) void rope_kernel(ushort* __restrict__ Q,
                                                   ushort* __restrict__ K,
                                                   const int* __restrict__ tpos) {
  int bid = blockIdx.x;
  ushort* buf = (bid & 1) ? K : Q;
  int idx = (bid >> 1) * 256 + threadIdx.x;
  int c = idx & 15;
  int row = idx >> 4;
  int s = row & (SEQ - 1);
  int bh = row >> 11;
  int b = bh >> 4;
  int pos = tpos[b * SEQ + s];
  int d0 = c * 8;
  ushort8 v = *(ushort8*)(buf + (size_t)row * DK + d0);
  float fp = (float)pos;
#pragma unroll
  for (int p = 0; p < 4; ++p) {
    int i = (d0 >> 1) + p;
    float freq = exp2f(-13.287712379549449f * ((float)i * (1.0f / 64.0f)));
    float ang = fp * freq;
    float sn, cs;
    sincosf(ang, &sn, &cs);
    float x1 = __builtin_bit_cast(float, (unsigned)v[2 * p] << 16);
    float x2 = __builtin_bit_cast(float, (unsigned)v[2 * p + 1] << 16);
    float r1 = x1 * cs - x2 * sn;
    float r2 = x1 * sn + x2 * cs;
    v[2 * p] = f2bf(r1);
    v[2 * p + 1] = f2bf(r2);
  }
  *(ushort8*)(buf + (size_t)row * DK + d0) = v;
}

// ---------------- V (B,H,S,DK) -> Vt (B,H,DK,S) ----------------
__global__ __launch_bounds__(256) void transpose_v(const ushort* __restrict__ Vb,
                                                   ushort* __restrict__ Vt) {
  __shared__ ushort t[64 * 80];
  int s0 = blockIdx.x * 64, d0 = blockIdx.y * 64, bh = blockIdx.z;
  const size_t base = (size_t)bh * SEQ * DK;
  int tid = threadIdx.x;
#pragma unroll
  for (int it = 0; it < 2; ++it) {
    int c = it * 256 + tid;
    int r = c >> 3, c8 = (c & 7) * 8;
    ushort8 v = *(const ushort8*)&Vb[base + (size_t)(s0 + r) * DK + d0 + c8];
    *(ushort8*)&t[r * 80 + c8] = v;
  }
  __syncthreads();
  const size_t obase = (size_t)bh * DK * SEQ;
#pragma unroll
  for (int it = 0; it < 2; ++it) {
    int c = it * 256 + tid;
    int dr = c >> 3, sc = (c & 7) * 8;
    ushort8 v;
#pragma unroll
    for (int i2 = 0; i2 < 8; ++i2) v[i2] = t[(sc + i2) * 80 + dr];
    *(ushort8*)&Vt[obase + (size_t)(d0 + dr) * SEQ + s0 + sc] = v;
  }
}

// ---------------- flash attention (causal), 4 waves/block, LDS-staged KV ----------------
__global__ __launch_bounds__(256, 2) void attn_kernel(const ushort* __restrict__ Qb,
                                                      const ushort* __restrict__ Kb,
                                                      const ushort* __restrict__ Vt,
                                                      ushort* __restrict__ attnb) {
  __shared__ ushort lds[32768];  // K bufs @0,8192; V^T bufs @16384,24576
  const int bx = blockIdx.x;
  const int u = bx & 255, hg = bx >> 8;
  const int qt = hg ? (15 - (u & 15)) : (u & 15);
  const int bh = (u >> 4) + hg * 16;
  const int tid = threadIdx.x;
  const int w = tid >> 6, lane = tid & 63;
  const int l31 = lane & 31, hi = lane >> 5;
  const int qb = qt * 128;
  const int qsb = qb + w * 32;
  const int q = qsb + l31;
  const size_t qk_base = (size_t)bh * SEQ * DK;
  const size_t v_base = (size_t)bh * DK * SEQ;
  const int nt = (qb + 128) >> 6;

  bf16x8 qf[8];
#pragma unroll
  for (int ks = 0; ks < 8; ++ks)
    qf[ks] = *(const bf16x8*)&Qb[qk_base + (size_t)q * DK + ks * 16 + hi * 8];

  f32x16 acc[4];
#pragma unroll
  for (int dt = 0; dt < 4; ++dt)
#pragma unroll
    for (int r = 0; r < 16; ++r) acc[dt][r] = 0.f;

  float m2 = -INFINITY, lsum = 0.f;
  const float cs2 = 0.08838834764831845f * 1.4426950408889634f;

  auto stage = [&](int t, int bufsel) {
    const int kb0 = t * 64;
#pragma unroll
    for (int i = 0; i < 4; ++i) {
      int g = w * 256 + i * 64 + lane;
      int row = g >> 4, c16 = g & 15;
      GLDS16(Kb + qk_base + (size_t)(kb0 + row) * DK + ((c16 ^ (row & 7)) * 8),
             &lds[bufsel * 8192 + (w * 256 + i * 64) * 8]);
    }
#pragma unroll
    for (int i = 0; i < 4; ++i) {
      int g = w * 256 + i * 64 + lane;
      int row = g >> 3, c8 = g & 7;
      GLDS16(Vt + v_base + (size_t)row * SEQ + kb0 + ((c8 ^ (row & 7)) * 8),
             &lds[16384 + bufsel * 8192 + (w * 256 + i * 64) * 8]);
    }
  };

  stage(0, 0);
  __syncthreads();
  int buf = 0;

  for (int t = 0; t < nt; ++t) {
    if (t + 1 < nt) stage(t + 1, buf ^ 1);
    const int kb0 = t * 64;
    if (kb0 <= qsb) {
      const ushort* lk = &lds[buf * 8192];
      const ushort* lv = &lds[16384 + buf * 8192];
      const int kb1 = kb0 + 32;
      const bool diag0 = (kb0 == qsb);
      const bool have1 = (kb1 <= qsb);
      const bool diag1 = (kb1 == qsb);
      const int sw = l31 & 7;

      f32x16 s0, s1;
#pragma unroll
      for (int r = 0; r < 16; ++r) { s0[r] = 0.f; s1[r] = 0.f; }
      __builtin_amdgcn_s_setprio(1);
#pragma unroll
      for (int ks = 0; ks < 8; ++ks) {
        int g = 2 * ks + hi;
        bf16x8 kf = *(const bf16x8*)&lk[(l31 * 16 + (g ^ sw)) * 8];
        s0 = __builtin_amdgcn_mfma_f32_32x32x16_bf16(kf, qf[ks], s0, 0, 0, 0);
      }
      if (have1) {
#pragma unroll
        for (int ks = 0; ks < 8; ++ks) {
          int g = 2 * ks + hi;
          bf16x8 kf = *(const bf16x8*)&lk[((32 + l31) * 16 + (g ^ sw)) * 8];
          s1 = __builtin_amdgcn_mfma_f32_32x32x16_bf16(kf, qf[ks], s1, 0, 0, 0);
        }
      }
      __builtin_amdgcn_s_setprio(0);

      float mx = -INFINITY;
#pragma unroll
      for (int r = 0; r < 16; ++r) {
        float v = s0[r] * cs2;
        if (diag0) {
          int kk = kb0 + (r & 3) + 8 * (r >> 2) + 4 * hi;
          if (kk > q) v = -INFINITY;
        }
        s0[r] = v;
        mx = fmaxf(mx, v);
      }
      if (have1) {
#pragma unroll
        for (int r = 0; r < 16; ++r) {
          float v = s1[r] * cs2;
          if (diag1) {
            int kk = kb1 + (r & 3) + 8 * (r >> 2) + 4 * hi;
            if (kk > q) v = -INFINITY;
          }
          s1[r] = v;
          mx = fmaxf(mx, v);
        }
      }
      mx = fmaxf(mx, __shfl_xor(mx, 32));

      float sc = 1.f;
      if (!__all(mx <= m2 + 11.5f)) {
        float mnew = fmaxf(m2, mx);
        sc = exp2f(m2 - mnew);
        m2 = mnew;
#pragma unroll
        for (int dt = 0; dt < 4; ++dt)
#pragma unroll
          for (int r = 0; r < 16; ++r) acc[dt][r] *= sc;
      }
      float rs = 0.f;
#pragma unroll
      for (int r = 0; r < 16; ++r) {
        float p = exp2f(s0[r] - m2);
        s0[r] = p;
        rs += p;
      }
      if (have1) {
#pragma unroll
        for (int r = 0; r < 16; ++r) {
          float p = exp2f(s1[r] - m2);
          s1[r] = p;
          rs += p;
        }
      }
      rs += __shfl_xor(rs, 32);
      lsum = lsum * sc + rs;

      unsigned w0[8], ws0[8];
#pragma unroll
      for (int i = 0; i < 8; ++i) w0[i] = cvtpk(s0[2 * i], s0[2 * i + 1]);
#pragma unroll
      for (int i = 0; i < 8; ++i) ws0[i] = (unsigned)__shfl_xor((int)w0[i], 32);
      u32x4 b00, b01;
      b00[0] = hi ? ws0[2] : w0[0]; b00[1] = hi ? ws0[3] : w0[1];
      b00[2] = hi ? w0[2] : ws0[0]; b00[3] = hi ? w0[3] : ws0[1];
      b01[0] = hi ? ws0[6] : w0[4]; b01[1] = hi ? ws0[7] : w0[5];
      b01[2] = hi ? w0[6] : ws0[4]; b01[3] = hi ? w0[7] : ws0[5];
      bf16x8 pb00 = __builtin_bit_cast(bf16x8, b00);
      bf16x8 pb01 = __builtin_bit_cast(bf16x8, b01);
      bf16x8 pb10, pb11;
      if (have1) {
        unsigned w1[8], ws1[8];
#pragma unroll
        for (int i = 0; i < 8; ++i) w1[i] = cvtpk(s1[2 * i], s1[2 * i + 1]);
#pragma unroll
        for (int i = 0; i < 8; ++i) ws1[i] = (unsigned)__shfl_xor((int)w1[i], 32);
        u32x4 b10, b11;
        b10[0] = hi ? ws1[2] : w1[0]; b10[1] = hi ? ws1[3] : w1[1];
        b10[2] = hi ? w1[2] : ws1[0]; b10[3] = hi ? w1[3] : ws1[1];
        b11[0] = hi ? ws1[6] : w1[4]; b11[1] = hi ? ws1[7] : w1[5];
        b11[2] = hi ? w1[6] : ws1[4]; b11[3] = hi ? w1[7] : ws1[5];
        pb10 = __builtin_bit_cast(bf16x8, b10);
        pb11 = __builtin_bit_cast(bf16x8, b11);
      }

      __builtin_amdgcn_s_setprio(1);
#pragma unroll
      for (int dt = 0; dt < 4; ++dt) {
        int vr = (dt * 32 + l31) * 8;
        bf16x8 vf0 = *(const bf16x8*)&lv[(vr + ((0 + hi) ^ sw)) * 8];
        bf16x8 vf1 = *(const bf16x8*)&lv[(vr + ((2 + hi) ^ sw)) * 8];
        acc[dt] = __builtin_amdgcn_mfma_f32_32x32x16_bf16(vf0, pb00, acc[dt], 0, 0, 0);
        acc[dt] = __builtin_amdgcn_mfma_f32_32x32x16_bf16(vf1, pb01, acc[dt], 0, 0, 0);
        if (have1) {
          bf16x8 vf2 = *(const bf16x8*)&lv[(vr + ((4 + hi) ^ sw)) * 8];
          bf16x8 vf3 = *(const bf16x8*)&lv[(vr + ((6 + hi) ^ sw)) * 8];
          acc[dt] = __builtin_amdgcn_mfma_f32_32x32x16_bf16(vf2, pb10, acc[dt], 0, 0, 0);
          acc[dt] = __builtin_amdgcn_mfma_f32_32x32x16_bf16(vf3, pb11, acc[dt], 0, 0, 0);
        }
      }
      __builtin_amdgcn_s_setprio(0);
    }
    __syncthreads();
    buf ^= 1;
  }

  ushort* eo = &lds[w * 32 * 136];
  float inv = 1.0f / lsum;
#pragma unroll
  for (int dt = 0; dt < 4; ++dt)
#pragma unroll
    for (int rq = 0; rq < 4; ++rq) {
      unsigned lo = cvtpk(acc[dt][4 * rq] * inv, acc[dt][4 * rq + 1] * inv);
      unsigned hh = cvtpk(acc[dt][4 * rq + 2] * inv, acc[dt][4 * rq + 3] * inv);
      uint2 pr; pr.x = lo; pr.y = hh;
      *(uint2*)&eo[l31 * 136 + dt * 32 + rq * 8 + hi * 4] = pr;
    }
  const int b = bh >> 4, h = bh & (NH - 1);
#pragma unroll
  for (int it = 0; it < 8; ++it) {
    int row = it * 4 + (lane >> 4);
    int c8 = (lane & 15) * 8;
    ushort8 v = *(const ushort8*)&eo[row * 136 + c8];
    *(ushort8*)&attnb[((size_t)b * SEQ + qsb + row) * DM + h * DK + c8] = v;
  }
}

extern "C" void kernel_launch(void* const* d_in, const int* in_sizes, int n_in,
                              void* d_out, int out_size, void* d_ws, size_t ws_size,
                              hipStream_t stream) {
  const float* x = (const float*)d_in[0];
  const int* tpos = (const int*)d_in[1];
  const float* WQ = (const float*)d_in[2];
  const float* WK = (const float*)d_in[3];
  const float* WV = (const float*)d_in[4];
  const float* WO = (const float*)d_in[5];
  float* out = (float*)d_out;
  char* ws = (char*)d_ws;

  ushort* xb  = (ushort*)(ws + 0);
  ushort* wqb = (ushort*)(ws + 16777216);
  ushort* wkb = (ushort*)(ws + 25165824);
  ushort* wvb = (ushort*)(ws + 33554432);
  ushort* wob = (ushort*)(ws + 41943040);
  ushort* Qb  = (ushort*)(ws + 50331648);
  ushort* Kb  = (ushort*)(ws + 67108864);
  ushort* Vb  = (ushort*)(ws + 83886080);
  ushort* Vt  = (ushort*)(ws + 0);           // alias xb (dead)
  ushort* attnb = (ushort*)(ws + 16777216);  // alias wqb+wkb (dead)

  hipFuncSetAttribute(reinterpret_cast<const void*>(gemmF_qkv),
                      hipFuncAttributeMaxDynamicSharedMemorySize, 65536);
  hipFuncSetAttribute(reinterpret_cast<const void*>(gemmF_out),
                      hipFuncAttributeMaxDynamicSharedMemorySize, 32768);

  cvt_all<<<12288, 256, 0, stream>>>(x, WQ, WK, WV, WO, xb, wqb, wkb, wvb, wob);

  gemmF_qkv<<<512, 512, 65536, stream>>>(xb, wqb, wkb, wvb, Qb, Kb, Vb);

  rope_kernel<<<8192, 256, 0, stream>>>(Qb, Kb, tpos);

  transpose_v<<<dim3(SEQ / 64, DK / 64, BATCH * NH), 256, 0, stream>>>(Vb, Vt);

  attn_kernel<<<dim3(512), 256, 0, stream>>>(Qb, Kb, Vt, attnb);

  gemmF_out<<<512, 512, 32768, stream>>>(attnb, wob, out);
}

// Round 7
// 261.716 us; speedup vs baseline: 1.4706x; 1.4706x over previous
//
#include <hip/hip_runtime.h>

typedef unsigned short ushort;
typedef __attribute__((ext_vector_type(8))) __bf16 bf16x8;
typedef __attribute__((ext_vector_type(8))) ushort ushort8;
typedef __attribute__((ext_vector_type(4))) float f32x4;
typedef __attribute__((ext_vector_type(16))) float f32x16;
typedef __attribute__((ext_vector_type(4))) unsigned u32x4;

#define DM 2048
#define NH 16
#define DK 128
#define BATCH 2
#define SEQ 2048
#define MROWS (BATCH*SEQ)   // 4096

#define GLDS16(g, l) __builtin_amdgcn_global_load_lds(                         \
    (const __attribute__((address_space(1))) void*)(g),                        \
    (__attribute__((address_space(3))) void*)(l), 16, 0, 0)

__device__ __forceinline__ ushort f2bf(float f) {
  unsigned u = __builtin_bit_cast(unsigned, f);
  u += 0x7fffu + ((u >> 16) & 1u);
  return (ushort)(u >> 16);
}

__device__ __forceinline__ unsigned cvtpk(float lo, float hi) {
  unsigned r;
  asm("v_cvt_pk_bf16_f32 %0, %1, %2" : "=v"(r) : "v"(lo), "v"(hi));
  return r;
}

// ---------------- f32 -> bf16 convert (x + 4 weights, one launch) ----------------
__global__ __launch_bounds__(256) void cvt_all(const float* __restrict__ x,
                                               const float* __restrict__ w0,
                                               const float* __restrict__ w1,
                                               const float* __restrict__ w2,
                                               const float* __restrict__ w3,
                                               ushort* __restrict__ xb,
                                               ushort* __restrict__ o0,
                                               ushort* __restrict__ o1,
                                               ushort* __restrict__ o2,
                                               ushort* __restrict__ o3) {
  int b = blockIdx.x;
  const float* src;
  ushort* dst;
  int lb;
  if (b < 4096) { src = x; dst = xb; lb = b; }
  else {
    int wsel = (b - 4096) >> 11;
    lb = (b - 4096) & 2047;
    src = (wsel == 0) ? w0 : (wsel == 1) ? w1 : (wsel == 2) ? w2 : w3;
    dst = (wsel == 0) ? o0 : (wsel == 1) ? o1 : (wsel == 2) ? o2 : o3;
  }
  int i = lb * 256 + threadIdx.x;
  const float4* p = (const float4*)src;
  float4 a = p[2 * i], bq = p[2 * i + 1];
  ushort8 o;
  o[0] = f2bf(a.x); o[1] = f2bf(a.y); o[2] = f2bf(a.z); o[3] = f2bf(a.w);
  o[4] = f2bf(bq.x); o[5] = f2bf(bq.y); o[6] = f2bf(bq.z); o[7] = f2bf(bq.w);
  *(ushort8*)(dst + (size_t)8 * i) = o;
}

// ---- fused multi-weight GEMM, BM=128 BN=128 BK=64, 8 waves (2M x 4N) ----
// C_w = A(MxK) * B_w^T for NW weights sharing A. Wave-tile 64 x (NFR*16) per weight.
// Double-buffered LDS (round-5 geometry: 0 conflicts, clean 49MB writes), but with
// COUNTED vmcnt: wait tile-t's loads (vmcnt LPT) BEFORE compute while tile-t+1 stays
// in flight across the barrier; stage(t+2) after the read-barrier. Never drain to 0
// in steady state. XOR-swizzled LDS granules (inverse-swizzled global source +
// swizzled ds_read). setprio around MFMA clusters.
// MODE 0: write bf16 scattered to (B,H,S,DK) per weight. MODE 1: write f32 MxN.
template <int NW, int NFR, int MODE>
__device__ __forceinline__ void gemmF_body(const ushort* __restrict__ A,
                                           const ushort* __restrict__ B0,
                                           const ushort* __restrict__ B1,
                                           const ushort* __restrict__ B2,
                                           ushort* __restrict__ O0,
                                           ushort* __restrict__ O1,
                                           ushort* __restrict__ O2,
                                           float* __restrict__ ofp,
                                           int row0, int col0) {
  extern __shared__ ushort lds[];
  constexpr int NT = DM / 64;                       // 32 K-tiles
  constexpr int BUFSZ = 8192 + NW * NFR * 4096;     // ushorts per buffer
  const ushort* Bw[3] = {B0, B1, B2};
  ushort* Ow[3] = {O0, O1, O2};
  const int tid = threadIdx.x;
  const int wid = tid >> 6, lane = tid & 63;
  const int l15 = lane & 15, lhi = lane >> 4;
  const int wm = wid >> 2, wn = wid & 3;
  const int swz = l15 & 7;

  f32x4 acc[4][NW * NFR];
  const f32x4 z4 = {0.f, 0.f, 0.f, 0.f};
#pragma unroll
  for (int mq = 0; mq < 4; ++mq)
#pragma unroll
    for (int i = 0; i < NW * NFR; ++i) acc[mq][i] = z4;

  auto stage = [&](int kt, int buf) {
    ushort* dstA = &lds[buf * BUFSZ];
    const ushort* srcA = A + (size_t)row0 * DM + kt * 64;
#pragma unroll
    for (int j = 0; j < 2; ++j) {
      int g = j * 512 + tid;
      int r = g >> 3, c = g & 7;
      GLDS16(srcA + (size_t)r * DM + ((c ^ (r & 7)) * 8),
             &dstA[(j * 512 + wid * 64) * 8]);
    }
#pragma unroll
    for (int w3 = 0; w3 < NW; ++w3) {
      ushort* dstB = &lds[buf * BUFSZ + 8192 + w3 * NFR * 4096];
      const ushort* srcB = Bw[w3] + (size_t)col0 * DM + kt * 64;
#pragma unroll
      for (int j = 0; j < NFR; ++j) {
        int g = j * 512 + tid;
        int r = g >> 3, c = g & 7;
        GLDS16(srcB + (size_t)r * DM + ((c ^ (r & 7)) * 8),
               &dstB[(j * 512 + wid * 64) * 8]);
      }
    }
  };

  stage(0, 0);
  stage(1, 1);

  for (int t = 0; t < NT; ++t) {
    // wait for tile t's loads only; tile t+1's stay in flight (T4 counted vmcnt)
    if (t + 1 < NT) {
      if constexpr (NW == 3)
        asm volatile("s_waitcnt vmcnt(8)" ::: "memory");
      else
        asm volatile("s_waitcnt vmcnt(6)" ::: "memory");
    } else {
      asm volatile("s_waitcnt vmcnt(0)" ::: "memory");
    }
    __builtin_amdgcn_s_barrier();  // all waves' tile-t loads landed

    const int cb = t & 1;
    const ushort* Ab = &lds[cb * BUFSZ];
    const ushort* Bb = Ab + 8192;
#pragma unroll
    for (int ks = 0; ks < 2; ++ks) {
      bf16x8 af[4];
#pragma unroll
      for (int mq = 0; mq < 4; ++mq) {
        int row = wm * 64 + mq * 16 + l15;
        af[mq] = *(const bf16x8*)&Ab[row * 64 + (((ks * 4 + lhi) ^ swz) * 8)];
      }
      bf16x8 bfr[NW * NFR];
#pragma unroll
      for (int w3 = 0; w3 < NW; ++w3)
#pragma unroll
        for (int n = 0; n < NFR; ++n) {
          int row = wn * (NFR * 16) + n * 16 + l15;
          bfr[w3 * NFR + n] =
              *(const bf16x8*)&Bb[w3 * NFR * 4096 + row * 64 + (((ks * 4 + lhi) ^ swz) * 8)];
        }
      __builtin_amdgcn_s_setprio(1);
#pragma unroll
      for (int mq = 0; mq < 4; ++mq)
#pragma unroll
        for (int i = 0; i < NW * NFR; ++i)
          acc[mq][i] = __builtin_amdgcn_mfma_f32_16x16x32_bf16(af[mq], bfr[i], acc[mq][i], 0, 0, 0);
      __builtin_amdgcn_s_setprio(0);
    }

    __builtin_amdgcn_s_barrier();  // all waves done reading buf[cb]
    if (t + 2 < NT) stage(t + 2, cb);
  }

  // epilogue
#pragma unroll
  for (int mq = 0; mq < 4; ++mq) {
    int grow = row0 + wm * 64 + mq * 16 + lhi * 4;
#pragma unroll
    for (int w3 = 0; w3 < NW; ++w3)
#pragma unroll
      for (int n = 0; n < NFR; ++n) {
        int gcol = col0 + wn * (NFR * 16) + n * 16 + l15;
#pragma unroll
        for (int j = 0; j < 4; ++j) {
          float v = acc[mq][w3 * NFR + n][j];
          int r = grow + j;
          if (MODE == 0) {
            int b = r >> 11, s = r & (SEQ - 1);
            int h = gcol >> 7, d = gcol & (DK - 1);
            Ow[w3][((size_t)(b * NH + h) * SEQ + s) * DK + d] = f2bf(v);
          } else {
            ofp[(size_t)r * DM + gcol] = v;
          }
        }
      }
  }
}

__global__ __launch_bounds__(512, 2) void gemmF_qkv(const ushort* __restrict__ A,
                                                    const ushort* __restrict__ W0,
                                                    const ushort* __restrict__ W1,
                                                    const ushort* __restrict__ W2,
                                                    ushort* __restrict__ O0,
                                                    ushort* __restrict__ O1,
                                                    ushort* __restrict__ O2) {
  // 512 blocks, grid 32r x 16c; XCD (bid&7) owns a 16-row x 4-col chunk
  // (minimizes per-XCD L2 fill: 16 A-panels + 4*3 weight col-panels per K-tile)
  int xcd = (int)blockIdx.x & 7, i = (int)blockIdx.x >> 3;  // i in [0,64)
  int row0 = (((xcd >> 2) << 4) + (i >> 2)) * 128;
  int col0 = (((xcd & 3) << 2) + (i & 3)) * 128;
  gemmF_body<3, 2, 0>(A, W0, W1, W2, O0, O1, O2, nullptr, row0, col0);
}

__global__ __launch_bounds__(512, 2) void gemmF_out(const ushort* __restrict__ A,
                                                    const ushort* __restrict__ Bm,
                                                    float* __restrict__ ofp) {
  // 256 blocks, grid 32r x 8c(x256); XCD owns an 8-row x 4-col chunk
  int xcd = (int)blockIdx.x & 7, i = (int)blockIdx.x >> 3;  // i in [0,32)
  int row0 = (((xcd >> 1) << 3) + (i >> 2)) * 128;
  int col0 = (((xcd & 1) << 2) + (i & 3)) * 256;
  gemmF_body<1, 4, 1>(A, Bm, nullptr, nullptr, nullptr, nullptr, nullptr, ofp, row0, col0);
}

// ---------------- RoPE in-place on Q and K, (B,H,S,DK) bf16, one launch ----------------
__global__ __launch_bounds__(256) void rope_kernel(ushort* __restrict__ Q,
                                                   ushort* __restrict__ K,
                                                   const int* __restrict__ tpos) {
  int bid = blockIdx.x;
  ushort* buf = (bid & 1) ? K : Q;
  int idx = (bid >> 1) * 256 + threadIdx.x;
  int c = idx & 15;
  int row = idx >> 4;
  int s = row & (SEQ - 1);
  int bh = row >> 11;
  int b = bh >> 4;
  int pos = tpos[b * SEQ + s];
  int d0 = c * 8;
  ushort8 v = *(ushort8*)(buf + (size_t)row * DK + d0);
  float fp = (float)pos;
#pragma unroll
  for (int p = 0; p < 4; ++p) {
    int i = (d0 >> 1) + p;
    float freq = exp2f(-13.287712379549449f * ((float)i * (1.0f / 64.0f)));
    float ang = fp * freq;
    float sn, cs;
    sincosf(ang, &sn, &cs);
    float x1 = __builtin_bit_cast(float, (unsigned)v[2 * p] << 16);
    float x2 = __builtin_bit_cast(float, (unsigned)v[2 * p + 1] << 16);
    float r1 = x1 * cs - x2 * sn;
    float r2 = x1 * sn + x2 * cs;
    v[2 * p] = f2bf(r1);
    v[2 * p + 1] = f2bf(r2);
  }
  *(ushort8*)(buf + (size_t)row * DK + d0) = v;
}

// ---------------- V (B,H,S,DK) -> Vt (B,H,DK,S) ----------------
__global__ __launch_bounds__(256) void transpose_v(const ushort* __restrict__ Vb,
                                                   ushort* __restrict__ Vt) {
  __shared__ ushort t[64 * 80];
  int s0 = blockIdx.x * 64, d0 = blockIdx.y * 64, bh = blockIdx.z;
  const size_t base = (size_t)bh * SEQ * DK;
  int tid = threadIdx.x;
#pragma unroll
  for (int it = 0; it < 2; ++it) {
    int c = it * 256 + tid;
    int r = c >> 3, c8 = (c & 7) * 8;
    ushort8 v = *(const ushort8*)&Vb[base + (size_t)(s0 + r) * DK + d0 + c8];
    *(ushort8*)&t[r * 80 + c8] = v;
  }
  __syncthreads();
  const size_t obase = (size_t)bh * DK * SEQ;
#pragma unroll
  for (int it = 0; it < 2; ++it) {
    int c = it * 256 + tid;
    int dr = c >> 3, sc = (c & 7) * 8;
    ushort8 v;
#pragma unroll
    for (int i2 = 0; i2 < 8; ++i2) v[i2] = t[(sc + i2) * 80 + dr];
    *(ushort8*)&Vt[obase + (size_t)(d0 + dr) * SEQ + s0 + sc] = v;
  }
}

// ---------------- flash attention (causal), 4 waves/block, LDS-staged KV ----------------
__global__ __launch_bounds__(256, 2) void attn_kernel(const ushort* __restrict__ Qb,
                                                      const ushort* __restrict__ Kb,
                                                      const ushort* __restrict__ Vt,
                                                      ushort* __restrict__ attnb) {
  __shared__ ushort lds[32768];  // K bufs @0,8192; V^T bufs @16384,24576
  const int bx = blockIdx.x;
  const int u = bx & 255, hg = bx >> 8;
  const int qt = hg ? (15 - (u & 15)) : (u & 15);
  const int bh = (u >> 4) + hg * 16;
  const int tid = threadIdx.x;
  const int w = tid >> 6, lane = tid & 63;
  const int l31 = lane & 31, hi = lane >> 5;
  const int qb = qt * 128;
  const int qsb = qb + w * 32;
  const int q = qsb + l31;
  const size_t qk_base = (size_t)bh * SEQ * DK;
  const size_t v_base = (size_t)bh * DK * SEQ;
  const int nt = (qb + 128) >> 6;

  bf16x8 qf[8];
#pragma unroll
  for (int ks = 0; ks < 8; ++ks)
    qf[ks] = *(const bf16x8*)&Qb[qk_base + (size_t)q * DK + ks * 16 + hi * 8];

  f32x16 acc[4];
#pragma unroll
  for (int dt = 0; dt < 4; ++dt)
#pragma unroll
    for (int r = 0; r < 16; ++r) acc[dt][r] = 0.f;

  float m2 = -INFINITY, lsum = 0.f;
  const float cs2 = 0.08838834764831845f * 1.4426950408889634f;

  auto stage = [&](int t, int bufsel) {
    const int kb0 = t * 64;
#pragma unroll
    for (int i = 0; i < 4; ++i) {
      int g = w * 256 + i * 64 + lane;
      int row = g >> 4, c16 = g & 15;
      GLDS16(Kb + qk_base + (size_t)(kb0 + row) * DK + ((c16 ^ (row & 7)) * 8),
             &lds[bufsel * 8192 + (w * 256 + i * 64) * 8]);
    }
#pragma unroll
    for (int i = 0; i < 4; ++i) {
      int g = w * 256 + i * 64 + lane;
      int row = g >> 3, c8 = g & 7;
      GLDS16(Vt + v_base + (size_t)row * SEQ + kb0 + ((c8 ^ (row & 7)) * 8),
             &lds[16384 + bufsel * 8192 + (w * 256 + i * 64) * 8]);
    }
  };

  stage(0, 0);
  __syncthreads();
  int buf = 0;

  for (int t = 0; t < nt; ++t) {
    if (t + 1 < nt) stage(t + 1, buf ^ 1);
    const int kb0 = t * 64;
    if (kb0 <= qsb) {
      const ushort* lk = &lds[buf * 8192];
      const ushort* lv = &lds[16384 + buf * 8192];
      const int kb1 = kb0 + 32;
      const bool diag0 = (kb0 == qsb);
      const bool have1 = (kb1 <= qsb);
      const bool diag1 = (kb1 == qsb);
      const int sw = l31 & 7;

      f32x16 s0, s1;
#pragma unroll
      for (int r = 0; r < 16; ++r) { s0[r] = 0.f; s1[r] = 0.f; }
      __builtin_amdgcn_s_setprio(1);
#pragma unroll
      for (int ks = 0; ks < 8; ++ks) {
        int g = 2 * ks + hi;
        bf16x8 kf = *(const bf16x8*)&lk[(l31 * 16 + (g ^ sw)) * 8];
        s0 = __builtin_amdgcn_mfma_f32_32x32x16_bf16(kf, qf[ks], s0, 0, 0, 0);
      }
      if (have1) {
#pragma unroll
        for (int ks = 0; ks < 8; ++ks) {
          int g = 2 * ks + hi;
          bf16x8 kf = *(const bf16x8*)&lk[((32 + l31) * 16 + (g ^ sw)) * 8];
          s1 = __builtin_amdgcn_mfma_f32_32x32x16_bf16(kf, qf[ks], s1, 0, 0, 0);
        }
      }
      __builtin_amdgcn_s_setprio(0);

      float mx = -INFINITY;
#pragma unroll
      for (int r = 0; r < 16; ++r) {
        float v = s0[r] * cs2;
        if (diag0) {
          int kk = kb0 + (r & 3) + 8 * (r >> 2) + 4 * hi;
          if (kk > q) v = -INFINITY;
        }
        s0[r] = v;
        mx = fmaxf(mx, v);
      }
      if (have1) {
#pragma unroll
        for (int r = 0; r < 16; ++r) {
          float v = s1[r] * cs2;
          if (diag1) {
            int kk = kb1 + (r & 3) + 8 * (r >> 2) + 4 * hi;
            if (kk > q) v = -INFINITY;
          }
          s1[r] = v;
          mx = fmaxf(mx, v);
        }
      }
      mx = fmaxf(mx, __shfl_xor(mx, 32));

      float sc = 1.f;
      if (!__all(mx <= m2 + 11.5f)) {
        float mnew = fmaxf(m2, mx);
        sc = exp2f(m2 - mnew);
        m2 = mnew;
#pragma unroll
        for (int dt = 0; dt < 4; ++dt)
#pragma unroll
          for (int r = 0; r < 16; ++r) acc[dt][r] *= sc;
      }
      float rs = 0.f;
#pragma unroll
      for (int r = 0; r < 16; ++r) {
        float p = exp2f(s0[r] - m2);
        s0[r] = p;
        rs += p;
      }
      if (have1) {
#pragma unroll
        for (int r = 0; r < 16; ++r) {
          float p = exp2f(s1[r] - m2);
          s1[r] = p;
          rs += p;
        }
      }
      rs += __shfl_xor(rs, 32);
      lsum = lsum * sc + rs;

      unsigned w0[8], ws0[8];
#pragma unroll
      for (int i = 0; i < 8; ++i) w0[i] = cvtpk(s0[2 * i], s0[2 * i + 1]);
#pragma unroll
      for (int i = 0; i < 8; ++i) ws0[i] = (unsigned)__shfl_xor((int)w0[i], 32);
      u32x4 b00, b01;
      b00[0] = hi ? ws0[2] : w0[0]; b00[1] = hi ? ws0[3] : w0[1];
      b00[2] = hi ? w0[2] : ws0[0]; b00[3] = hi ? w0[3] : ws0[1];
      b01[0] = hi ? ws0[6] : w0[4]; b01[1] = hi ? ws0[7] : w0[5];
      b01[2] = hi ? w0[6] : ws0[4]; b01[3] = hi ? w0[7] : ws0[5];
      bf16x8 pb00 = __builtin_bit_cast(bf16x8, b00);
      bf16x8 pb01 = __builtin_bit_cast(bf16x8, b01);
      bf16x8 pb10, pb11;
      if (have1) {
        unsigned w1[8], ws1[8];
#pragma unroll
        for (int i = 0; i < 8; ++i) w1[i] = cvtpk(s1[2 * i], s1[2 * i + 1]);
#pragma unroll
        for (int i = 0; i < 8; ++i) ws1[i] = (unsigned)__shfl_xor((int)w1[i], 32);
        u32x4 b10, b11;
        b10[0] = hi ? ws1[2] : w1[0]; b10[1] = hi ? ws1[3] : w1[1];
        b10[2] = hi ? w1[2] : ws1[0]; b10[3] = hi ? w1[3] : ws1[1];
        b11[0] = hi ? ws1[6] : w1[4]; b11[1] = hi ? ws1[7] : w1[5];
        b11[2] = hi ? w1[6] : ws1[4]; b11[3] = hi ? w1[7] : ws1[5];
        pb10 = __builtin_bit_cast(bf16x8, b10);
        pb11 = __builtin_bit_cast(bf16x8, b11);
      }

      __builtin_amdgcn_s_setprio(1);
#pragma unroll
      for (int dt = 0; dt < 4; ++dt) {
        int vr = (dt * 32 + l31) * 8;
        bf16x8 vf0 = *(const bf16x8*)&lv[(vr + ((0 + hi) ^ sw)) * 8];
        bf16x8 vf1 = *(const bf16x8*)&lv[(vr + ((2 + hi) ^ sw)) * 8];
        acc[dt] = __builtin_amdgcn_mfma_f32_32x32x16_bf16(vf0, pb00, acc[dt], 0, 0, 0);
        acc[dt] = __builtin_amdgcn_mfma_f32_32x32x16_bf16(vf1, pb01, acc[dt], 0, 0, 0);
        if (have1) {
          bf16x8 vf2 = *(const bf16x8*)&lv[(vr + ((4 + hi) ^ sw)) * 8];
          bf16x8 vf3 = *(const bf16x8*)&lv[(vr + ((6 + hi) ^ sw)) * 8];
          acc[dt] = __builtin_amdgcn_mfma_f32_32x32x16_bf16(vf2, pb10, acc[dt], 0, 0, 0);
          acc[dt] = __builtin_amdgcn_mfma_f32_32x32x16_bf16(vf3, pb11, acc[dt], 0, 0, 0);
        }
      }
      __builtin_amdgcn_s_setprio(0);
    }
    __syncthreads();
    buf ^= 1;
  }

  ushort* eo = &lds[w * 32 * 136];
  float inv = 1.0f / lsum;
#pragma unroll
  for (int dt = 0; dt < 4; ++dt)
#pragma unroll
    for (int rq = 0; rq < 4; ++rq) {
      unsigned lo = cvtpk(acc[dt][4 * rq] * inv, acc[dt][4 * rq + 1] * inv);
      unsigned hh = cvtpk(acc[dt][4 * rq + 2] * inv, acc[dt][4 * rq + 3] * inv);
      uint2 pr; pr.x = lo; pr.y = hh;
      *(uint2*)&eo[l31 * 136 + dt * 32 + rq * 8 + hi * 4] = pr;
    }
  const int b = bh >> 4, h = bh & (NH - 1);
#pragma unroll
  for (int it = 0; it < 8; ++it) {
    int row = it * 4 + (lane >> 4);
    int c8 = (lane & 15) * 8;
    ushort8 v = *(const ushort8*)&eo[row * 136 + c8];
    *(ushort8*)&attnb[((size_t)b * SEQ + qsb + row) * DM + h * DK + c8] = v;
  }
}

extern "C" void kernel_launch(void* const* d_in, const int* in_sizes, int n_in,
                              void* d_out, int out_size, void* d_ws, size_t ws_size,
                              hipStream_t stream) {
  const float* x = (const float*)d_in[0];
  const int* tpos = (const int*)d_in[1];
  const float* WQ = (const float*)d_in[2];
  const float* WK = (const float*)d_in[3];
  const float* WV = (const float*)d_in[4];
  const float* WO = (const float*)d_in[5];
  float* out = (float*)d_out;
  char* ws = (char*)d_ws;

  ushort* xb  = (ushort*)(ws + 0);
  ushort* wqb = (ushort*)(ws + 16777216);
  ushort* wkb = (ushort*)(ws + 25165824);
  ushort* wvb = (ushort*)(ws + 33554432);
  ushort* wob = (ushort*)(ws + 41943040);
  ushort* Qb  = (ushort*)(ws + 50331648);
  ushort* Kb  = (ushort*)(ws + 67108864);
  ushort* Vb  = (ushort*)(ws + 83886080);
  ushort* Vt  = (ushort*)(ws + 0);           // alias xb (dead)
  ushort* attnb = (ushort*)(ws + 16777216);  // alias wqb+wkb (dead)

  hipFuncSetAttribute(reinterpret_cast<const void*>(gemmF_qkv),
                      hipFuncAttributeMaxDynamicSharedMemorySize, 131072);
  hipFuncSetAttribute(reinterpret_cast<const void*>(gemmF_out),
                      hipFuncAttributeMaxDynamicSharedMemorySize, 98304);

  cvt_all<<<12288, 256, 0, stream>>>(x, WQ, WK, WV, WO, xb, wqb, wkb, wvb, wob);

  gemmF_qkv<<<512, 512, 131072, stream>>>(xb, wqb, wkb, wvb, Qb, Kb, Vb);

  rope_kernel<<<8192, 256, 0, stream>>>(Qb, Kb, tpos);

  transpose_v<<<dim3(SEQ / 64, DK / 64, BATCH * NH), 256, 0, stream>>>(Vb, Vt);

  attn_kernel<<<dim3(512), 256, 0, stream>>>(Qb, Kb, Vt, attnb);

  gemmF_out<<<256, 512, 98304, stream>>>(attnb, wob, out);
}